// Round 9
// baseline (1662.541 us; speedup 1.0000x reference)
//
#include <hip/hip_runtime.h>
#include <stdint.h>

// FP8 SwiGLU MLP. Round 7 kernel (2nd resubmit — infra failures): 2-phase
// double-buffered staging with counted vmcnt (T3 minimal), BM=256 geometry
// (AI up 33%), GY=4 supertile rasterization for L3 weight residency.
// MX-scaled fp8 MFMA (K=128, unit e8m0 scales).
//
// Shapes: B*S = M = 8192, H = 4096, I = 11008.

typedef float f32x4 __attribute__((ext_vector_type(4)));
typedef int   i32x4 __attribute__((ext_vector_type(4)));
typedef int   i32x8 __attribute__((ext_vector_type(8)));
typedef unsigned int u32;

#define AS1 __attribute__((address_space(1)))
#define AS3 __attribute__((address_space(3)))

#define BM 256
#define BN 128
#define BKB 128   // K-bytes per step (fp8: 128 elements = one MX K-step)

#define SCALE1 0x7F7F7F7F  // e8m0 = 127 -> 2^0 in every byte

__device__ __forceinline__ void gld_lds16(const uint8_t* g, uint8_t* l) {
  __builtin_amdgcn_global_load_lds((const AS1 u32*)g, (AS3 u32*)l, 16, 0, 0);
}

__device__ __forceinline__ uint8_t f32_to_fp8(float v) {
  v = fminf(fmaxf(v, -448.f), 448.f);
  int r = __builtin_amdgcn_cvt_pk_fp8_f32(v, v, 0, false);
  return (uint8_t)(r & 0xff);
}

// read one lane's 32-byte K-chunk (two swizzled 16B halves) as v8i32
__device__ __forceinline__ i32x8 read_frag32(const uint8_t* s, int row, int ko, int swz) {
  const uint8_t* p = s + row * BKB;
  i32x4 lo = *(const i32x4*)(p + ((ko) ^ swz));
  i32x4 hi = *(const i32x4*)(p + ((ko + 16) ^ swz));
  return __builtin_shufflevector(lo, hi, 0, 1, 2, 3, 4, 5, 6, 7);
}

// ---------------- quantize f32 -> fp8 bytes (8 elems/thread) ----------------
__global__ __launch_bounds__(256) void quant_fp8_k(const float* __restrict__ in,
                                                   uint8_t* __restrict__ out,
                                                   const float* __restrict__ scale_ptr,
                                                   long n8) {
  long i = (long)blockIdx.x * 256 + threadIdx.x;
  if (i >= n8) return;
  float inv = scale_ptr ? (1.0f / scale_ptr[0]) : 1.0f;
  const float4* p = (const float4*)(in + i * 8);
  float4 a = p[0], b = p[1];
  float v0 = fminf(fmaxf(a.x * inv, -448.f), 448.f);
  float v1 = fminf(fmaxf(a.y * inv, -448.f), 448.f);
  float v2 = fminf(fmaxf(a.z * inv, -448.f), 448.f);
  float v3 = fminf(fmaxf(a.w * inv, -448.f), 448.f);
  float v4 = fminf(fmaxf(b.x * inv, -448.f), 448.f);
  float v5 = fminf(fmaxf(b.y * inv, -448.f), 448.f);
  float v6 = fminf(fmaxf(b.z * inv, -448.f), 448.f);
  float v7 = fminf(fmaxf(b.w * inv, -448.f), 448.f);
  int lo = __builtin_amdgcn_cvt_pk_fp8_f32(v0, v1, 0, false);
  lo = __builtin_amdgcn_cvt_pk_fp8_f32(v2, v3, lo, true);
  int hi = __builtin_amdgcn_cvt_pk_fp8_f32(v4, v5, 0, false);
  hi = __builtin_amdgcn_cvt_pk_fp8_f32(v6, v7, hi, true);
  ((int2*)out)[i] = make_int2(lo, hi);
}

// ---------------- fused dual GEMM1 + SwiGLU + fp8 requant ----------------
// 512 threads, 8 waves (4x2 grid of 64x64 wave-tiles), 2-phase dbuf LDS.
__global__ __launch_bounds__(512, 2) void gemm1_swiglu(
    const uint8_t* __restrict__ Xq,   // [M][H]
    const uint8_t* __restrict__ Gq,   // [I][H]
    const uint8_t* __restrict__ Uq,   // [I][H]
    uint8_t* __restrict__ Hq,         // [M][I]
    const float* __restrict__ gws, const float* __restrict__ uws,
    const float* __restrict__ gis, const float* __restrict__ uis,
    const float* __restrict__ dis,
    int M, int H, int I) {
  __shared__ uint8_t sX[2][BM * BKB];   // 2 x 32KB
  __shared__ uint8_t sG[2][BN * BKB];   // 2 x 16KB
  __shared__ uint8_t sU[2][BN * BKB];   // 2 x 16KB  -> 128KB total

  const int tid = threadIdx.x;
  const int wave = tid >> 6, lane = tid & 63;
  const int wr = wave >> 1, wc = wave & 1;      // 4x2 wave grid, 64x64 each
  const int lrow = lane & 15;
  const int lkg = lane >> 4;
  const int swz = (lrow & 7) << 4;
  const int koB = lkg * 32;

  // supertile rasterization: GY=4 y-blocks share weight panels back-to-back
  const int nbx = I / BN;               // 86
  const int GY = 4;
  const int per = nbx * GY;             // 344
  const int grp = blockIdx.x / per, rem = blockIdx.x % per;
  const int xb = rem / GY, yb = grp * GY + (rem % GY);
  const int bM = yb * BM, bN = xb * BN;

  f32x4 accG[4][4] = {};
  f32x4 accU[4][4] = {};

  const uint8_t* gx = Xq + (size_t)bM * H;
  const uint8_t* gg = Gq + (size_t)bN * H;
  const uint8_t* gu = Uq + (size_t)bN * H;

  // 8 gld_lds16 issues per thread per STAGE (4 sX + 2 sG + 2 sU)
  auto STAGE = [&](int buf, int k0) {
#pragma unroll
    for (int it = 0; it < 4; ++it) {
      int c = it * 512 + tid;
      int r = c >> 3;                        // 0..255
      int col = ((c & 7) ^ (r & 7)) * 16;    // pre-swizzled source
      gld_lds16(gx + (size_t)r * H + k0 + col, &sX[buf][(it * 8 + wave) * 1024]);
    }
#pragma unroll
    for (int it = 0; it < 2; ++it) {
      int c = it * 512 + tid;
      int r = c >> 3;                        // 0..127
      int col = ((c & 7) ^ (r & 7)) * 16;
      gld_lds16(gg + (size_t)r * H + k0 + col, &sG[buf][(it * 8 + wave) * 1024]);
      gld_lds16(gu + (size_t)r * H + k0 + col, &sU[buf][(it * 8 + wave) * 1024]);
    }
  };

  const int NK = H / BKB;                    // 32
  STAGE(0, 0);
  for (int step = 0; step < NK; ++step) {
    const int cur = step & 1;
    if (step + 1 < NK) {
      STAGE(cur ^ 1, (step + 1) * BKB);      // prefetch next tile (8 issues)
      asm volatile("s_waitcnt vmcnt(8)" ::: "memory");   // cur's loads done
    } else {
      asm volatile("s_waitcnt vmcnt(0)" ::: "memory");
    }
    __syncthreads();

    i32x8 af[4];
#pragma unroll
    for (int i = 0; i < 4; ++i)
      af[i] = read_frag32(sX[cur], wr * 64 + i * 16 + lrow, koB, swz);
#pragma unroll
    for (int j = 0; j < 4; ++j) {
      i32x8 gf = read_frag32(sG[cur], wc * 64 + j * 16 + lrow, koB, swz);
      i32x8 uf = read_frag32(sU[cur], wc * 64 + j * 16 + lrow, koB, swz);
#pragma unroll
      for (int i = 0; i < 4; ++i) {
        accG[i][j] = __builtin_amdgcn_mfma_scale_f32_16x16x128_f8f6f4(
            af[i], gf, accG[i][j], 0, 0, 0, SCALE1, 0, SCALE1);
        accU[i][j] = __builtin_amdgcn_mfma_scale_f32_16x16x128_f8f6f4(
            af[i], uf, accU[i][j], 0, 0, 0, SCALE1, 0, SCALE1);
      }
    }
    __syncthreads();   // compute done before next STAGE overwrites buf[cur^1^1]
  }

  const float sg = gws[0] * gis[0];
  const float su = uws[0] * uis[0];
  const float invd = 1.0f / dis[0];

  uint8_t* sH = sX[0];             // 32KB staging for the 256x128 fp8 out-tile

#pragma unroll
  for (int i = 0; i < 4; ++i)
#pragma unroll
    for (int j = 0; j < 4; ++j)
#pragma unroll
      for (int t = 0; t < 4; ++t) {
        float g = accG[i][j][t] * sg;
        float u = accU[i][j][t] * su;
        float h = (g / (1.0f + expf(-g))) * u * invd;
        int row = wr * 64 + i * 16 + lkg * 4 + t;   // C: col=lane&15, row=(lane>>4)*4+t
        int col = wc * 64 + j * 16 + lrow;
        sH[row * BN + col] = f32_to_fp8(h);
      }
  __syncthreads();
#pragma unroll
  for (int it = 0; it < 4; ++it) {
    int o = (it * 512 + tid) * 16;
    int row = o >> 7, col = o & 127;
    *(int4*)(Hq + (size_t)(bM + row) * I + bN + col) = *(const int4*)(sH + o);
  }
}

// ---------------- GEMM2: out[m,hd] = (sum_i Hq[m,i]*Dq[hd,i]) * ds ----------------
__global__ __launch_bounds__(512, 2) void gemm2_down(
    const uint8_t* __restrict__ Hq,   // [M][I]
    const uint8_t* __restrict__ Dq,   // [Hd][I]
    float* __restrict__ Out,          // [M][Hd]
    const float* __restrict__ dws, const float* __restrict__ dis,
    int M, int I, int Hd) {
  __shared__ uint8_t sA[2][BM * BKB];   // 2 x 32KB
  __shared__ uint8_t sB[2][BN * BKB];   // 2 x 16KB -> 96KB

  const int tid = threadIdx.x;
  const int wave = tid >> 6, lane = tid & 63;
  const int wr = wave >> 1, wc = wave & 1;
  const int lrow = lane & 15;
  const int lkg = lane >> 4;
  const int swz = (lrow & 7) << 4;
  const int koB = lkg * 32;

  const int nbx = Hd / BN;              // 32
  const int GY = 4;
  const int per = nbx * GY;             // 128
  const int grp = blockIdx.x / per, rem = blockIdx.x % per;
  const int xb = rem / GY, yb = grp * GY + (rem % GY);
  const int bM = yb * BM, bN = xb * BN;

  f32x4 acc[4][4] = {};

  const uint8_t* ga = Hq + (size_t)bM * I;
  const uint8_t* gb = Dq + (size_t)bN * I;

  // 6 issues per thread per STAGE (4 sA + 2 sB)
  auto STAGE = [&](int buf, int k0) {
#pragma unroll
    for (int it = 0; it < 4; ++it) {
      int c = it * 512 + tid;
      int r = c >> 3;
      int col = ((c & 7) ^ (r & 7)) * 16;
      gld_lds16(ga + (size_t)r * I + k0 + col, &sA[buf][(it * 8 + wave) * 1024]);
    }
#pragma unroll
    for (int it = 0; it < 2; ++it) {
      int c = it * 512 + tid;
      int r = c >> 3;
      int col = ((c & 7) ^ (r & 7)) * 16;
      gld_lds16(gb + (size_t)r * I + k0 + col, &sB[buf][(it * 8 + wave) * 1024]);
    }
  };

  const int NK = I / BKB;               // 86
  STAGE(0, 0);
  for (int step = 0; step < NK; ++step) {
    const int cur = step & 1;
    if (step + 1 < NK) {
      STAGE(cur ^ 1, (step + 1) * BKB);
      asm volatile("s_waitcnt vmcnt(6)" ::: "memory");
    } else {
      asm volatile("s_waitcnt vmcnt(0)" ::: "memory");
    }
    __syncthreads();

    i32x8 af[4];
#pragma unroll
    for (int i = 0; i < 4; ++i)
      af[i] = read_frag32(sA[cur], wr * 64 + i * 16 + lrow, koB, swz);
#pragma unroll
    for (int j = 0; j < 4; ++j) {
      i32x8 bf = read_frag32(sB[cur], wc * 64 + j * 16 + lrow, koB, swz);
#pragma unroll
      for (int i = 0; i < 4; ++i)
        acc[i][j] = __builtin_amdgcn_mfma_scale_f32_16x16x128_f8f6f4(
            af[i], bf, acc[i][j], 0, 0, 0, SCALE1, 0, SCALE1);
    }
    __syncthreads();
  }

  const float ds = dws[0] * dis[0];
#pragma unroll
  for (int i = 0; i < 4; ++i)
#pragma unroll
    for (int j = 0; j < 4; ++j) {
      int row = bM + wr * 64 + i * 16 + lkg * 4;
      int col = bN + wc * 64 + j * 16 + lrow;
#pragma unroll
      for (int t = 0; t < 4; ++t)
        Out[(size_t)(row + t) * Hd + col] = acc[i][j][t] * ds;
    }
}

extern "C" void kernel_launch(void* const* d_in, const int* in_sizes, int n_in,
                              void* d_out, int out_size, void* d_ws, size_t ws_size,
                              hipStream_t stream) {
  const float* x   = (const float*)d_in[0];
  const float* gw  = (const float*)d_in[1];
  const float* uw  = (const float*)d_in[2];
  const float* dw  = (const float*)d_in[3];
  const float* gws = (const float*)d_in[4];
  const float* uws = (const float*)d_in[5];
  const float* dws = (const float*)d_in[6];
  const float* gis = (const float*)d_in[7];
  const float* uis = (const float*)d_in[8];
  const float* dis = (const float*)d_in[9];

  const int Hd = 4096;
  const int M  = in_sizes[0] / Hd;          // 8192
  const int I  = in_sizes[1] / Hd;          // 11008

  const size_t szX = (size_t)M * Hd;        // 33.5 MB
  const size_t szW = (size_t)I * Hd;        // 45.1 MB
  const size_t szH = (size_t)M * I;         // 90.2 MB

  uint8_t* xq = (uint8_t*)d_ws;
  uint8_t* gq = xq + szX;
  uint8_t* uq = gq + szW;
  uint8_t* hq = uq + szW;
  uint8_t* dq = gq;                         // reuse gate slot after GEMM1

  if (ws_size < szX + 2 * szW + szH) return;  // fail loudly (out stays poisoned)

  float* out = (float*)d_out;

  // 1. quantize activations and GEMM1 weights
  {
    long n8 = (long)(szX / 8);
    quant_fp8_k<<<dim3((n8 + 255) / 256), dim3(256), 0, stream>>>(x, xq, gis, n8);
  }
  {
    long n8 = (long)(szW / 8);
    quant_fp8_k<<<dim3((n8 + 255) / 256), dim3(256), 0, stream>>>(gw, gq, nullptr, n8);
    quant_fp8_k<<<dim3((n8 + 255) / 256), dim3(256), 0, stream>>>(uw, uq, nullptr, n8);
  }

  // 2. fused gate/up GEMM + SwiGLU + fp8 requant of hidden
  gemm1_swiglu<<<dim3((I / BN) * (M / BM)), dim3(512), 0, stream>>>(
      xq, gq, uq, hq, gws, uws, gis, uis, dis, M, Hd, I);

  // 3. quantize down weights (into gate slot), then down GEMM
  {
    long n8 = (long)(szW / 8);
    quant_fp8_k<<<dim3((n8 + 255) / 256), dim3(256), 0, stream>>>(dw, dq, nullptr, n8);
  }
  gemm2_down<<<dim3((Hd / BN) * (M / BM)), dim3(512), 0, stream>>>(
      hq, dq, out, dws, dis, M, I, Hd);
}

// Round 10
// 1539.473 us; speedup vs baseline: 1.0799x; 1.0799x over previous
//
#include <hip/hip_runtime.h>
#include <stdint.h>

// FP8 SwiGLU MLP. Round 10: restore 2 blocks/CU (R9 lesson: 128KB LDS -> 1
// block/CU lost inter-block overlap and regressed). Gate/up weights are
// INTERLEAVED in 16-row groups at quant time, so gemm1 is a standard GEMM
// (N = 2*I) with in-lane gate/up pairing in the epilogue. Both GEMMs: 128x128
// tile, 2-phase double-buffered LDS (64KB -> 2 blocks/CU) with counted
// vmcnt(8), GY=4 supertile raster (verified FETCH halver), MX fp8 MFMA K=128.
//
// Shapes: B*S = M = 8192, H = 4096, I = 11008, N2 = 2*I = 22016.

typedef float f32x4 __attribute__((ext_vector_type(4)));
typedef int   i32x4 __attribute__((ext_vector_type(4)));
typedef int   i32x8 __attribute__((ext_vector_type(8)));
typedef unsigned int u32;

#define AS1 __attribute__((address_space(1)))
#define AS3 __attribute__((address_space(3)))

#define TM 128
#define TN 128
#define BKB 128   // K-bytes per step (one MX K=128 step)

#define SCALE1 0x7F7F7F7F  // e8m0 = 127 -> 2^0 in every byte

__device__ __forceinline__ void gld_lds16(const uint8_t* g, uint8_t* l) {
  __builtin_amdgcn_global_load_lds((const AS1 u32*)g, (AS3 u32*)l, 16, 0, 0);
}

__device__ __forceinline__ uint8_t f32_to_fp8(float v) {
  v = fminf(fmaxf(v, -448.f), 448.f);
  int r = __builtin_amdgcn_cvt_pk_fp8_f32(v, v, 0, false);
  return (uint8_t)(r & 0xff);
}

// read one lane's 32-byte K-chunk (two swizzled 16B halves) as v8i32
__device__ __forceinline__ i32x8 read_frag32(const uint8_t* s, int row, int ko, int swz) {
  const uint8_t* p = s + row * BKB;
  i32x4 lo = *(const i32x4*)(p + ((ko) ^ swz));
  i32x4 hi = *(const i32x4*)(p + ((ko + 16) ^ swz));
  return __builtin_shufflevector(lo, hi, 0, 1, 2, 3, 4, 5, 6, 7);
}

__device__ __forceinline__ int2 quant8(const float* in, long e0, float inv) {
  const float4* p = (const float4*)(in + e0);
  float4 a = p[0], b = p[1];
  float v0 = fminf(fmaxf(a.x * inv, -448.f), 448.f);
  float v1 = fminf(fmaxf(a.y * inv, -448.f), 448.f);
  float v2 = fminf(fmaxf(a.z * inv, -448.f), 448.f);
  float v3 = fminf(fmaxf(a.w * inv, -448.f), 448.f);
  float v4 = fminf(fmaxf(b.x * inv, -448.f), 448.f);
  float v5 = fminf(fmaxf(b.y * inv, -448.f), 448.f);
  float v6 = fminf(fmaxf(b.z * inv, -448.f), 448.f);
  float v7 = fminf(fmaxf(b.w * inv, -448.f), 448.f);
  int lo = __builtin_amdgcn_cvt_pk_fp8_f32(v0, v1, 0, false);
  lo = __builtin_amdgcn_cvt_pk_fp8_f32(v2, v3, lo, true);
  int hi = __builtin_amdgcn_cvt_pk_fp8_f32(v4, v5, 0, false);
  hi = __builtin_amdgcn_cvt_pk_fp8_f32(v6, v7, hi, true);
  return make_int2(lo, hi);
}

// ---------------- flat quantize f32 -> fp8 (row-preserving) ----------------
__global__ __launch_bounds__(256) void quant_fp8_k(const float* __restrict__ in,
                                                   uint8_t* __restrict__ out,
                                                   const float* __restrict__ scale_ptr,
                                                   long n8) {
  long i = (long)blockIdx.x * 256 + threadIdx.x;
  if (i >= n8) return;
  float inv = scale_ptr ? (1.0f / scale_ptr[0]) : 1.0f;
  ((int2*)out)[i] = quant8(in, i * 8, inv);
}

// ------- interleaving quantize: route row r -> 32*(r/16) + phase*16 + r%16 -------
__global__ __launch_bounds__(256) void quant_fp8_ileave(const float* __restrict__ in,
                                                        uint8_t* __restrict__ out,
                                                        int phase, int Hc, long n8) {
  long i = (long)blockIdx.x * 256 + threadIdx.x;
  if (i >= n8) return;
  long e0 = i * 8;
  long r = e0 / Hc;                  // input row
  long col = e0 - r * Hc;            // 8-aligned within row
  long ro = ((r >> 4) << 5) + ((long)phase << 4) + (r & 15);
  ((int2*)(out))[(ro * Hc + col) >> 3] = quant8(in, e0, 1.0f);
}

// ---------------- fused GEMM1 (interleaved W2) + SwiGLU + fp8 requant ----------------
// C = Xq @ W2^T over N2=2I; j-fragments alternate gate/up for the same I-range.
__global__ __launch_bounds__(256, 2) void gemm1_swiglu(
    const uint8_t* __restrict__ Xq,   // [M][H]
    const uint8_t* __restrict__ W2q,  // [2I][H] interleaved 16-row groups
    uint8_t* __restrict__ Hq,         // [M][I]
    const float* __restrict__ gws, const float* __restrict__ uws,
    const float* __restrict__ gis, const float* __restrict__ uis,
    const float* __restrict__ dis,
    int M, int H, int I) {
  __shared__ uint8_t sX[2][TM * BKB];   // 2 x 16KB
  __shared__ uint8_t sW[2][TN * BKB];   // 2 x 16KB -> 64KB total

  const int tid = threadIdx.x;
  const int wave = tid >> 6, lane = tid & 63;
  const int wr = wave >> 1, wc = wave & 1;      // 2x2 wave grid, 64x64 each
  const int lrow = lane & 15;
  const int lkg = lane >> 4;
  const int swz = (lrow & 7) << 4;
  const int koB = lkg * 32;

  const int N2 = 2 * I;
  const int nbx = N2 / TN;              // 172
  const int GY = 4;
  const int per = nbx * GY;             // 688
  const int grp = blockIdx.x / per, rem = blockIdx.x % per;
  const int xb = rem / GY, yb = grp * GY + (rem % GY);
  const int bM = yb * TM, bN2 = xb * TN;

  f32x4 acc[4][4] = {};

  const uint8_t* gx = Xq + (size_t)bM * H;
  const uint8_t* gw = W2q + (size_t)bN2 * H;

  // 8 gld_lds16 issues per thread per STAGE (4 sX + 4 sW)
  auto STAGE = [&](int buf, int k0) {
#pragma unroll
    for (int it = 0; it < 4; ++it) {
      int c = it * 256 + tid;
      int r = c >> 3;                        // 0..127
      int col = ((c & 7) ^ (r & 7)) * 16;    // pre-swizzled source
      gld_lds16(gx + (size_t)r * H + k0 + col, &sX[buf][(it * 4 + wave) * 1024]);
    }
#pragma unroll
    for (int it = 0; it < 4; ++it) {
      int c = it * 256 + tid;
      int r = c >> 3;
      int col = ((c & 7) ^ (r & 7)) * 16;
      gld_lds16(gw + (size_t)r * H + k0 + col, &sW[buf][(it * 4 + wave) * 1024]);
    }
  };

  const int NK = H / BKB;                    // 32
  STAGE(0, 0);
  for (int step = 0; step < NK; ++step) {
    const int cur = step & 1;
    if (step + 1 < NK) {
      STAGE(cur ^ 1, (step + 1) * BKB);      // prefetch next tile (8 issues)
      asm volatile("s_waitcnt vmcnt(8)" ::: "memory");   // cur's loads done
    } else {
      asm volatile("s_waitcnt vmcnt(0)" ::: "memory");
    }
    __syncthreads();

    i32x8 af[4];
#pragma unroll
    for (int i = 0; i < 4; ++i)
      af[i] = read_frag32(sX[cur], wr * 64 + i * 16 + lrow, koB, swz);
#pragma unroll
    for (int j = 0; j < 4; ++j) {
      i32x8 wf = read_frag32(sW[cur], wc * 64 + j * 16 + lrow, koB, swz);
#pragma unroll
      for (int i = 0; i < 4; ++i)
        acc[i][j] = __builtin_amdgcn_mfma_scale_f32_16x16x128_f8f6f4(
            af[i], wf, acc[i][j], 0, 0, 0, SCALE1, 0, SCALE1);
    }
    __syncthreads();   // all reads of buf cur done before next STAGE overwrites it
  }

  const float sg = gws[0] * gis[0];
  const float su = uws[0] * uis[0];
  const float invd = 1.0f / dis[0];

  uint8_t* sH = (uint8_t*)sX;      // 8KB staging for the 128x64 fp8 out-tile

  // j=2t is gate, j=2t+1 is up, SAME lane, same I-range: colI = (wc*2+t)*16+lrow
#pragma unroll
  for (int i = 0; i < 4; ++i)
#pragma unroll
    for (int t = 0; t < 2; ++t)
#pragma unroll
      for (int tt = 0; tt < 4; ++tt) {
        float g = acc[i][2 * t][tt] * sg;
        float u = acc[i][2 * t + 1][tt] * su;
        float h = (g / (1.0f + expf(-g))) * u * invd;
        int row = wr * 64 + i * 16 + lkg * 4 + tt;   // C: col=lane&15, row=(lane>>4)*4+tt
        int colI = (wc * 2 + t) * 16 + lrow;         // 0..63
        sH[row * 64 + colI] = f32_to_fp8(h);
      }
  __syncthreads();
#pragma unroll
  for (int it = 0; it < 2; ++it) {
    int o = (it * 256 + tid) * 16;
    int row = o >> 6, col = o & 63;
    *(int4*)(Hq + (size_t)(bM + row) * I + (bN2 >> 1) + col) = *(const int4*)(sH + o);
  }
}

// ---------------- GEMM2: out[m,hd] = (sum_i Hq[m,i]*Dq[hd,i]) * ds ----------------
__global__ __launch_bounds__(256, 2) void gemm2_down(
    const uint8_t* __restrict__ Hq,   // [M][I]
    const uint8_t* __restrict__ Dq,   // [Hd][I]
    float* __restrict__ Out,          // [M][Hd]
    const float* __restrict__ dws, const float* __restrict__ dis,
    int M, int I, int Hd) {
  __shared__ uint8_t sA[2][TM * BKB];   // 2 x 16KB
  __shared__ uint8_t sB[2][TN * BKB];   // 2 x 16KB -> 64KB

  const int tid = threadIdx.x;
  const int wave = tid >> 6, lane = tid & 63;
  const int wr = wave >> 1, wc = wave & 1;
  const int lrow = lane & 15;
  const int lkg = lane >> 4;
  const int swz = (lrow & 7) << 4;
  const int koB = lkg * 32;

  const int nbx = Hd / TN;              // 32
  const int GY = 4;
  const int per = nbx * GY;             // 128
  const int grp = blockIdx.x / per, rem = blockIdx.x % per;
  const int xb = rem / GY, yb = grp * GY + (rem % GY);
  const int bM = yb * TM, bN = xb * TN;

  f32x4 acc[4][4] = {};

  const uint8_t* ga = Hq + (size_t)bM * I;
  const uint8_t* gb = Dq + (size_t)bN * I;

  // 8 issues per thread per STAGE (4 sA + 4 sB)
  auto STAGE = [&](int buf, int k0) {
#pragma unroll
    for (int it = 0; it < 4; ++it) {
      int c = it * 256 + tid;
      int r = c >> 3;
      int col = ((c & 7) ^ (r & 7)) * 16;
      gld_lds16(ga + (size_t)r * I + k0 + col, &sA[buf][(it * 4 + wave) * 1024]);
    }
#pragma unroll
    for (int it = 0; it < 4; ++it) {
      int c = it * 256 + tid;
      int r = c >> 3;
      int col = ((c & 7) ^ (r & 7)) * 16;
      gld_lds16(gb + (size_t)r * I + k0 + col, &sB[buf][(it * 4 + wave) * 1024]);
    }
  };

  const int NK = I / BKB;               // 86
  STAGE(0, 0);
  for (int step = 0; step < NK; ++step) {
    const int cur = step & 1;
    if (step + 1 < NK) {
      STAGE(cur ^ 1, (step + 1) * BKB);
      asm volatile("s_waitcnt vmcnt(8)" ::: "memory");
    } else {
      asm volatile("s_waitcnt vmcnt(0)" ::: "memory");
    }
    __syncthreads();

    i32x8 af[4];
#pragma unroll
    for (int i = 0; i < 4; ++i)
      af[i] = read_frag32(sA[cur], wr * 64 + i * 16 + lrow, koB, swz);
#pragma unroll
    for (int j = 0; j < 4; ++j) {
      i32x8 bf = read_frag32(sB[cur], wc * 64 + j * 16 + lrow, koB, swz);
#pragma unroll
      for (int i = 0; i < 4; ++i)
        acc[i][j] = __builtin_amdgcn_mfma_scale_f32_16x16x128_f8f6f4(
            af[i], bf, acc[i][j], 0, 0, 0, SCALE1, 0, SCALE1);
    }
    __syncthreads();
  }

  const float ds = dws[0] * dis[0];
#pragma unroll
  for (int i = 0; i < 4; ++i)
#pragma unroll
    for (int j = 0; j < 4; ++j) {
      int row = bM + wr * 64 + i * 16 + lkg * 4;
      int col = bN + wc * 64 + j * 16 + lrow;
#pragma unroll
      for (int t = 0; t < 4; ++t)
        Out[(size_t)(row + t) * Hd + col] = acc[i][j][t] * ds;
    }
}

extern "C" void kernel_launch(void* const* d_in, const int* in_sizes, int n_in,
                              void* d_out, int out_size, void* d_ws, size_t ws_size,
                              hipStream_t stream) {
  const float* x   = (const float*)d_in[0];
  const float* gw  = (const float*)d_in[1];
  const float* uw  = (const float*)d_in[2];
  const float* dw  = (const float*)d_in[3];
  const float* gws = (const float*)d_in[4];
  const float* uws = (const float*)d_in[5];
  const float* dws = (const float*)d_in[6];
  const float* gis = (const float*)d_in[7];
  const float* uis = (const float*)d_in[8];
  const float* dis = (const float*)d_in[9];

  const int Hd = 4096;
  const int M  = in_sizes[0] / Hd;          // 8192
  const int I  = in_sizes[1] / Hd;          // 11008

  const size_t szX = (size_t)M * Hd;        // 33.5 MB
  const size_t szW = (size_t)I * Hd;        // 45.1 MB
  const size_t szH = (size_t)M * I;         // 90.2 MB

  uint8_t* xq  = (uint8_t*)d_ws;
  uint8_t* w2q = xq + szX;                  // 2*szW interleaved gate/up
  uint8_t* hq  = w2q + 2 * szW;
  uint8_t* dq  = w2q;                       // reuse after gemm1

  if (ws_size < szX + 2 * szW + szH) return;  // fail loudly (out stays poisoned)

  float* out = (float*)d_out;

  // 1. quantize activations (flat) and gate/up weights (interleaved)
  {
    long n8 = (long)(szX / 8);
    quant_fp8_k<<<dim3((n8 + 255) / 256), dim3(256), 0, stream>>>(x, xq, gis, n8);
  }
  {
    long n8 = (long)(szW / 8);
    quant_fp8_ileave<<<dim3((n8 + 255) / 256), dim3(256), 0, stream>>>(gw, w2q, 0, Hd, n8);
    quant_fp8_ileave<<<dim3((n8 + 255) / 256), dim3(256), 0, stream>>>(uw, w2q, 1, Hd, n8);
  }

  // 2. fused gate/up GEMM + SwiGLU + fp8 requant of hidden
  gemm1_swiglu<<<dim3((2 * I / TN) * (M / TM)), dim3(256), 0, stream>>>(
      xq, w2q, hq, gws, uws, gis, uis, dis, M, Hd, I);

  // 3. quantize down weights (into w2q slot), then down GEMM
  {
    long n8 = (long)(szW / 8);
    quant_fp8_k<<<dim3((n8 + 255) / 256), dim3(256), 0, stream>>>(dw, dq, nullptr, n8);
  }
  gemm2_down<<<dim3((Hd / TN) * (M / TM)), dim3(256), 0, stream>>>(
      hq, dq, out, dws, dis, M, I, Hd);
}

// Round 11
// 1282.373 us; speedup vs baseline: 1.2965x; 1.2005x over previous
//
#include <hip/hip_runtime.h>
#include <stdint.h>

// FP8 SwiGLU MLP. Round 11: revert gemm1 to the proven R6 dual-GEMM (shared-X
// staging, 48KB single-buffer, 74% of MX ceiling) + GY=4 supertile raster.
// gemm2 rebuilt in the same high-AI shape: TN=256 dual B-panel sharing the A
// staging (48KB, 32 MFMAs/wave-step) + raster. MX fp8 MFMA K=128, unit scales.
//
// Shapes: B*S = M = 8192, H = 4096, I = 11008.

typedef float f32x4 __attribute__((ext_vector_type(4)));
typedef int   i32x4 __attribute__((ext_vector_type(4)));
typedef int   i32x8 __attribute__((ext_vector_type(8)));
typedef unsigned int u32;

#define AS1 __attribute__((address_space(1)))
#define AS3 __attribute__((address_space(3)))

#define TM 128
#define TN 128
#define BKB 128   // K-bytes per step (one MX K=128 step)

#define SCALE1 0x7F7F7F7F  // e8m0 = 127 -> 2^0 in every byte

__device__ __forceinline__ void gld_lds16(const uint8_t* g, uint8_t* l) {
  __builtin_amdgcn_global_load_lds((const AS1 u32*)g, (AS3 u32*)l, 16, 0, 0);
}

__device__ __forceinline__ uint8_t f32_to_fp8(float v) {
  v = fminf(fmaxf(v, -448.f), 448.f);
  int r = __builtin_amdgcn_cvt_pk_fp8_f32(v, v, 0, false);
  return (uint8_t)(r & 0xff);
}

// read one lane's 32-byte K-chunk (two swizzled 16B halves) as v8i32
__device__ __forceinline__ i32x8 read_frag32(const uint8_t* s, int row, int ko, int swz) {
  const uint8_t* p = s + row * BKB;
  i32x4 lo = *(const i32x4*)(p + ((ko) ^ swz));
  i32x4 hi = *(const i32x4*)(p + ((ko + 16) ^ swz));
  return __builtin_shufflevector(lo, hi, 0, 1, 2, 3, 4, 5, 6, 7);
}

// ---------------- quantize f32 -> fp8 bytes (8 elems/thread) ----------------
__global__ __launch_bounds__(256) void quant_fp8_k(const float* __restrict__ in,
                                                   uint8_t* __restrict__ out,
                                                   const float* __restrict__ scale_ptr,
                                                   long n8) {
  long i = (long)blockIdx.x * 256 + threadIdx.x;
  if (i >= n8) return;
  float inv = scale_ptr ? (1.0f / scale_ptr[0]) : 1.0f;
  const float4* p = (const float4*)(in + i * 8);
  float4 a = p[0], b = p[1];
  float v0 = fminf(fmaxf(a.x * inv, -448.f), 448.f);
  float v1 = fminf(fmaxf(a.y * inv, -448.f), 448.f);
  float v2 = fminf(fmaxf(a.z * inv, -448.f), 448.f);
  float v3 = fminf(fmaxf(a.w * inv, -448.f), 448.f);
  float v4 = fminf(fmaxf(b.x * inv, -448.f), 448.f);
  float v5 = fminf(fmaxf(b.y * inv, -448.f), 448.f);
  float v6 = fminf(fmaxf(b.z * inv, -448.f), 448.f);
  float v7 = fminf(fmaxf(b.w * inv, -448.f), 448.f);
  int lo = __builtin_amdgcn_cvt_pk_fp8_f32(v0, v1, 0, false);
  lo = __builtin_amdgcn_cvt_pk_fp8_f32(v2, v3, lo, true);
  int hi = __builtin_amdgcn_cvt_pk_fp8_f32(v4, v5, 0, false);
  hi = __builtin_amdgcn_cvt_pk_fp8_f32(v6, v7, hi, true);
  ((int2*)out)[i] = make_int2(lo, hi);
}

// ---------------- fused dual GEMM1 + SwiGLU + fp8 requant (R6 structure) ----------------
__global__ __launch_bounds__(256, 2) void gemm1_swiglu(
    const uint8_t* __restrict__ Xq,   // [M][H]
    const uint8_t* __restrict__ Gq,   // [I][H]
    const uint8_t* __restrict__ Uq,   // [I][H]
    uint8_t* __restrict__ Hq,         // [M][I]
    const float* __restrict__ gws, const float* __restrict__ uws,
    const float* __restrict__ gis, const float* __restrict__ uis,
    const float* __restrict__ dis,
    int M, int H, int I) {
  __shared__ uint8_t sX[TM * BKB];
  __shared__ uint8_t sG[TN * BKB];
  __shared__ uint8_t sU[TN * BKB];

  const int tid = threadIdx.x;
  const int wave = tid >> 6, lane = tid & 63;
  const int wr = wave >> 1, wc = wave & 1;      // 2x2 wave grid, 64x64 each
  const int lrow = lane & 15;
  const int lkg = lane >> 4;
  const int swz = (lrow & 7) << 4;
  const int ko = lkg * 32;

  // GY=4 supertile raster: 4 consecutive blocks share one weight panel
  const int nbx = I / TN;               // 86
  const int GY = 4;
  const int per = nbx * GY;             // 344
  const int grp = blockIdx.x / per, rem = blockIdx.x % per;
  const int xb = rem / GY, yb = grp * GY + (rem % GY);   // bijective: (M/TM)%GY==0
  const int bM = yb * TM, bN = xb * TN;

  f32x4 accG[4][4] = {};
  f32x4 accU[4][4] = {};

  const uint8_t* gx = Xq + (size_t)bM * H;
  const uint8_t* gg = Gq + (size_t)bN * H;
  const uint8_t* gu = Uq + (size_t)bN * H;

  for (int k0 = 0; k0 < H; k0 += BKB) {
    if (k0) __syncthreads();
#pragma unroll
    for (int it = 0; it < 4; ++it) {
      int c = it * 256 + tid;                // 16B chunk index within 16KB tile
      int r = c >> 3;                        // row (128B rows -> 8 chunks/row)
      int col = ((c & 7) ^ (r & 7)) * 16;    // pre-swizzled global source
      size_t go = (size_t)r * H + k0 + col;
      int lo = (it * 4 + wave) * 1024;       // wave-uniform linear LDS base
      gld_lds16(gx + go, sX + lo);
      gld_lds16(gg + go, sG + lo);
      gld_lds16(gu + go, sU + lo);
    }
    asm volatile("s_waitcnt vmcnt(0)" ::: "memory");
    __syncthreads();

    i32x8 af[4];
#pragma unroll
    for (int i = 0; i < 4; ++i)
      af[i] = read_frag32(sX, wr * 64 + i * 16 + lrow, ko, swz);
#pragma unroll
    for (int j = 0; j < 4; ++j) {
      i32x8 gf = read_frag32(sG, wc * 64 + j * 16 + lrow, ko, swz);
      i32x8 uf = read_frag32(sU, wc * 64 + j * 16 + lrow, ko, swz);
#pragma unroll
      for (int i = 0; i < 4; ++i) {
        accG[i][j] = __builtin_amdgcn_mfma_scale_f32_16x16x128_f8f6f4(
            af[i], gf, accG[i][j], 0, 0, 0, SCALE1, 0, SCALE1);
        accU[i][j] = __builtin_amdgcn_mfma_scale_f32_16x16x128_f8f6f4(
            af[i], uf, accU[i][j], 0, 0, 0, SCALE1, 0, SCALE1);
      }
    }
  }

  const float sg = gws[0] * gis[0];
  const float su = uws[0] * uis[0];
  const float invd = 1.0f / dis[0];

  __syncthreads();                 // everyone done reading LDS tiles
  uint8_t* sH = sX;                // reuse 16KB as output staging (linear)

#pragma unroll
  for (int i = 0; i < 4; ++i)
#pragma unroll
    for (int j = 0; j < 4; ++j)
#pragma unroll
      for (int t = 0; t < 4; ++t) {
        float g = accG[i][j][t] * sg;
        float u = accU[i][j][t] * su;
        float h = (g / (1.0f + expf(-g))) * u * invd;
        int row = wr * 64 + i * 16 + lkg * 4 + t;   // C: col=lane&15, row=(lane>>4)*4+t
        int col = wc * 64 + j * 16 + lrow;
        sH[row * TN + col] = f32_to_fp8(h);
      }
  __syncthreads();
#pragma unroll
  for (int it = 0; it < 4; ++it) {
    int o = (it * 256 + tid) * 16;
    int row = o >> 7, col = o & 127;
    *(int4*)(Hq + (size_t)(bM + row) * I + bN + col) = *(const int4*)(sH + o);
  }
}

// ---------------- GEMM2: dual B-panel (TN=256) sharing A staging ----------------
// out[m,hd] = (sum_i Hq[m,i]*Dq[hd,i]) * ds, 128x256 tile, 48KB single-buffer.
__global__ __launch_bounds__(256, 2) void gemm2_down(
    const uint8_t* __restrict__ Hq,   // [M][I]
    const uint8_t* __restrict__ Dq,   // [Hd][I]
    float* __restrict__ Out,          // [M][Hd]
    const float* __restrict__ dws, const float* __restrict__ dis,
    int M, int I, int Hd) {
  __shared__ uint8_t sA[TM * BKB];        // 16KB
  __shared__ uint8_t sB[2 * TN * BKB];    // 32KB (256 B-rows)

  const int tid = threadIdx.x;
  const int wave = tid >> 6, lane = tid & 63;
  const int wr = wave >> 1, wc = wave & 1;   // wave-tile: 64 rows x 128 cols
  const int lrow = lane & 15;
  const int lkg = lane >> 4;
  const int swz = (lrow & 7) << 4;
  const int ko = lkg * 32;

  const int TNW = 256;                  // N per block
  const int nbx = Hd / TNW;             // 16
  const int GY = 4;
  const int per = nbx * GY;             // 64
  const int grp = blockIdx.x / per, rem = blockIdx.x % per;
  const int xb = rem / GY, yb = grp * GY + (rem % GY);   // (M/TM)%GY==0 -> bijective
  const int bM = yb * TM, bN = xb * TNW;

  f32x4 acc[4][8] = {};

  const uint8_t* ga = Hq + (size_t)bM * I;
  const uint8_t* gb = Dq + (size_t)bN * I;

  for (int k0 = 0; k0 < I; k0 += BKB) {
    if (k0) __syncthreads();
#pragma unroll
    for (int it = 0; it < 4; ++it) {       // A: 128 rows, 16KB
      int c = it * 256 + tid;
      int r = c >> 3;
      int col = ((c & 7) ^ (r & 7)) * 16;
      gld_lds16(ga + (size_t)r * I + k0 + col, sA + (it * 4 + wave) * 1024);
    }
#pragma unroll
    for (int it = 0; it < 8; ++it) {       // B: 256 rows, 32KB
      int c = it * 256 + tid;
      int r = c >> 3;
      int col = ((c & 7) ^ (r & 7)) * 16;
      gld_lds16(gb + (size_t)r * I + k0 + col, sB + (it * 4 + wave) * 1024);
    }
    asm volatile("s_waitcnt vmcnt(0)" ::: "memory");
    __syncthreads();

    i32x8 af[4];
#pragma unroll
    for (int i = 0; i < 4; ++i)
      af[i] = read_frag32(sA, wr * 64 + i * 16 + lrow, ko, swz);
#pragma unroll
    for (int j = 0; j < 8; ++j) {
      i32x8 bf = read_frag32(sB, wc * 128 + j * 16 + lrow, ko, swz);
#pragma unroll
      for (int i = 0; i < 4; ++i)
        acc[i][j] = __builtin_amdgcn_mfma_scale_f32_16x16x128_f8f6f4(
            af[i], bf, acc[i][j], 0, 0, 0, SCALE1, 0, SCALE1);
    }
  }

  const float ds = dws[0] * dis[0];
#pragma unroll
  for (int i = 0; i < 4; ++i)
#pragma unroll
    for (int j = 0; j < 8; ++j) {
      int row = bM + wr * 64 + i * 16 + lkg * 4;
      int col = bN + wc * 128 + j * 16 + lrow;
#pragma unroll
      for (int t = 0; t < 4; ++t)
        Out[(size_t)(row + t) * Hd + col] = acc[i][j][t] * ds;
    }
}

extern "C" void kernel_launch(void* const* d_in, const int* in_sizes, int n_in,
                              void* d_out, int out_size, void* d_ws, size_t ws_size,
                              hipStream_t stream) {
  const float* x   = (const float*)d_in[0];
  const float* gw  = (const float*)d_in[1];
  const float* uw  = (const float*)d_in[2];
  const float* dw  = (const float*)d_in[3];
  const float* gws = (const float*)d_in[4];
  const float* uws = (const float*)d_in[5];
  const float* dws = (const float*)d_in[6];
  const float* gis = (const float*)d_in[7];
  const float* uis = (const float*)d_in[8];
  const float* dis = (const float*)d_in[9];

  const int Hd = 4096;
  const int M  = in_sizes[0] / Hd;          // 8192
  const int I  = in_sizes[1] / Hd;          // 11008

  const size_t szX = (size_t)M * Hd;        // 33.5 MB
  const size_t szW = (size_t)I * Hd;        // 45.1 MB
  const size_t szH = (size_t)M * I;         // 90.2 MB

  uint8_t* xq = (uint8_t*)d_ws;
  uint8_t* gq = xq + szX;
  uint8_t* uq = gq + szW;
  uint8_t* hq = uq + szW;
  uint8_t* dq = gq;                         // reuse gate slot after GEMM1

  if (ws_size < szX + 2 * szW + szH) return;  // fail loudly (out stays poisoned)

  float* out = (float*)d_out;

  // 1. quantize activations and GEMM1 weights
  {
    long n8 = (long)(szX / 8);
    quant_fp8_k<<<dim3((n8 + 255) / 256), dim3(256), 0, stream>>>(x, xq, gis, n8);
  }
  {
    long n8 = (long)(szW / 8);
    quant_fp8_k<<<dim3((n8 + 255) / 256), dim3(256), 0, stream>>>(gw, gq, nullptr, n8);
    quant_fp8_k<<<dim3((n8 + 255) / 256), dim3(256), 0, stream>>>(uw, uq, nullptr, n8);
  }

  // 2. fused gate/up GEMM + SwiGLU + fp8 requant of hidden
  gemm1_swiglu<<<dim3((I / TN) * (M / TM)), dim3(256), 0, stream>>>(
      xq, gq, uq, hq, gws, uws, gis, uis, dis, M, Hd, I);

  // 3. quantize down weights (into gate slot), then down GEMM
  {
    long n8 = (long)(szW / 8);
    quant_fp8_k<<<dim3((n8 + 255) / 256), dim3(256), 0, stream>>>(dw, dq, nullptr, n8);
  }
  gemm2_down<<<dim3((Hd / 256) * (M / TM)), dim3(256), 0, stream>>>(
      hq, dq, out, dws, dis, M, I, Hd);
}